// Round 9
// baseline (56.090 us; speedup 1.0000x reference)
//
#include <hip/hip_runtime.h>

#define B_    64
#define C_    23
#define E_    1024
#define D_    1024
#define BOT_  128
#define BINS_ 8192
#define S_    3
#define NUMBINS (C_*BINS_)

typedef float f32x4 __attribute__((ext_vector_type(4)));

// ws layout (floats):
// [0,384)            M  : M[s*128+k]   = sum_d Wfc[s][d]      * Wb[d][k]
// [512,512+3072)     N  : N[s*1024+e]  = sum_d Wfc[s][1024+d] * We[d][e]
// [3584,3587)        c0 : c0[s]
// [3600,3600+4416)   pe : pe[(b*C+c)*3+s]
#define WS_M   0
#define WS_N   512
#define WS_C0  3584
#define WS_PE  3600

// grid 73: [0,64): N (e0 = bx*16, all 3 s)  [64,72): M (k0=(bx-64)*16)  72: c0
__global__ __launch_bounds__(256) void kprep(const float* __restrict__ Wb,
                                             const float* __restrict__ We,
                                             const float* __restrict__ be,
                                             const float* __restrict__ Wfc,
                                             const float* __restrict__ bfc,
                                             float* __restrict__ ws) {
    const int bx = blockIdx.x;
    const int t  = threadIdx.x;

    if (bx == 72) {                // c0
        int wave = t >> 6, lane = t & 63;
        if (wave < 3) {
            const float* w2 = Wfc + wave * 2 * D_ + D_;
            float acc = 0.f;
            #pragma unroll
            for (int j = 0; j < D_ / 64; j++) {
                int d = lane + j * 64;
                acc += w2[d] * be[d];
            }
            #pragma unroll
            for (int off = 32; off; off >>= 1) acc += __shfl_down(acc, off);
            if (lane == 0) ws[WS_C0 + wave] = acc + bfc[wave];
        }
        return;
    }

    __shared__ float wv[3072];     // 3 broadcast rows of Wfc (w1 or w2)
    __shared__ float red[256];

    const int og   = t & 15;       // output within the 16-chunk
    const int dgrp = t >> 4;       // 0..15, each owns 64 d's

    const float* src;              // matrix: src[d*ostride + obase + og]
    int ostride, obase, wofs;
    float* dst0;                   // + s*dstride
    int dstride;

    if (bx < 64) {                 // N[s][e0+og]
        int e0 = bx * 16;
        src = We; ostride = E_; obase = e0; wofs = D_;
        dst0 = ws + WS_N + e0; dstride = E_;
    } else {                       // M[s][k0+og]
        int k0 = (bx - 64) * 16;
        src = Wb; ostride = BOT_; obase = k0; wofs = 0;
        dst0 = ws + WS_M + k0; dstride = BOT_;
    }

    for (int i = t; i < 3072; i += 256) {
        int s = i >> 10, d = i & 1023;
        wv[i] = Wfc[s * 2 * D_ + wofs + d];
    }
    __syncthreads();

    const float* p  = src + (size_t)(dgrp * 64) * ostride + obase + og;
    const float* w0 = wv + dgrp * 64;
    float a0 = 0.f, a1 = 0.f, a2 = 0.f;
    #pragma unroll 8
    for (int i = 0; i < 64; i++) {
        float v = p[(size_t)i * ostride];
        a0 += w0[i] * v;
        a1 += w0[1024 + i] * v;
        a2 += w0[2048 + i] * v;
    }
    float accs[3] = {a0, a1, a2};
    for (int s = 0; s < 3; s++) {
        __syncthreads();
        red[t] = accs[s];
        #pragma unroll
        for (int off = 128; off >= 16; off >>= 1) {
            __syncthreads();
            if (t < off) red[t] += red[t + off];
        }
        if (t < 16) dst0[s * dstride + t] = red[t];
    }
}

// one wave per (b,c) row: pe = eos_emb[row]·N[s] + c0[s]
__global__ __launch_bounds__(256) void kpe(const float* __restrict__ eos,
                                           float* ws) {
    int wave = threadIdx.x >> 6;
    int lane = threadIdx.x & 63;
    int row  = blockIdx.x * 4 + wave;      // 0..B*C-1 (=1471)
    const float* x  = eos + (size_t)row * E_;
    const float* N0 = ws + WS_N;
    float a0 = 0.f, a1 = 0.f, a2 = 0.f;
    #pragma unroll
    for (int j = 0; j < E_ / 64; j++) {
        int i = lane + j * 64;
        float v = x[i];
        a0 += v * N0[i];
        a1 += v * N0[1024 + i];
        a2 += v * N0[2048 + i];
    }
    #pragma unroll
    for (int off = 32; off; off >>= 1) {
        a0 += __shfl_down(a0, off);
        a1 += __shfl_down(a1, off);
        a2 += __shfl_down(a2, off);
    }
    if (lane == 0) {
        float* pe = ws + WS_PE + row * 3;
        pe[0] = a0 + ws[WS_C0 + 0];
        pe[1] = a1 + ws[WS_C0 + 1];
        pe[2] = a2 + ws[WS_C0 + 2];
    }
}

// grid (32, 23): block = (c=blockIdx.y, n0 = blockIdx.x*256).
// BARRIER-FREE main loop: each wave owns rows [n0+w*64, +64) end-to-end.
// Per 16-row chunk: coalesced 1KB/instr loads (next chunk prefetched, stays
// in flight -- no barrier ever drains vmcnt), per-lane partial-quad written
// with ONE ds_write_b128 into a wave-private strip, wave-local reduce
// (same-wave DS is in-order; lgkmcnt only), then the chunk's 64-b output
// slice is NT-streamed immediately. Waves de-synchronize -> reads+writes
// mix continuously. Single __syncthreads (pel init) before any heavy loads.
__global__ __launch_bounds__(256) void kmain(const float* __restrict__ table,
                                             const float* __restrict__ ws,
                                             float* __restrict__ out) {
    const int t  = threadIdx.x;
    const int c  = blockIdx.y;
    const int n0 = blockIdx.x * 256;

    const int w  = t >> 6;         // wave 0..3
    const int l  = t & 63;
    const int h  = l >> 5;         // row parity within pair
    const int kk = l & 31;         // f32x4 quad within row

    __shared__ f32x4 P4[4][16 * 33];   // wave-private partial strips (33-quad row stride)
    __shared__ float pbw[4][192];      // wave-private pb[row_local*3+s]
    __shared__ float pel[192];         // pe[b*3+s] for this c (shared, read-only)

    // pel init FIRST, then the only barrier (so it never drains table loads)
    if (t < 192) {
        int b = t / 3, s = t - b * 3;
        pel[t] = ws[WS_PE + (b * C_ + c) * 3 + s];
    }
    __syncthreads();

    // per-lane M coefficients: M[s][kk*4 .. kk*4+3]
    f32x4 M0 = ((const f32x4*)(ws + WS_M      ))[kk];
    f32x4 M1 = ((const f32x4*)(ws + WS_M + 128))[kk];
    f32x4 M2 = ((const f32x4*)(ws + WS_M + 256))[kk];

    const float* base = table + (size_t)(1 + c * BINS_ + n0 + w * 64) * BOT_ + kk * 4;
    float* ob = out + ((size_t)c * BINS_ + n0 + w * 64) * 3;
    f32x4* pstrip = P4[w];
    float* pw = pbw[w];

    f32x4 ra[8], rb[8];
    #pragma unroll
    for (int i = 0; i < 8; i++)
        ra[i] = *(const f32x4*)(base + (size_t)(i * 2 + h) * BOT_);

    #pragma unroll
    for (int cc = 0; cc < 4; cc++) {
        // prefetch next chunk (stays in flight across compute+reduce+stores)
        if (cc < 3) {
            #pragma unroll
            for (int i = 0; i < 8; i++) {
                f32x4 ld = *(const f32x4*)(base + (size_t)((cc + 1) * 16 + i * 2 + h) * BOT_);
                if (cc & 1) ra[i] = ld; else rb[i] = ld;
            }
        }
        // partials for this chunk: one b128 write per (2-row pair)
        #pragma unroll
        for (int i = 0; i < 8; i++) {
            f32x4 v = (cc & 1) ? rb[i] : ra[i];
            int rl = i * 2 + h;
            f32x4 p;
            p.x = v.x * M0.x + v.y * M0.y + v.z * M0.z + v.w * M0.w;
            p.y = v.x * M1.x + v.y * M1.y + v.z * M1.z + v.w * M1.w;
            p.z = v.x * M2.x + v.y * M2.y + v.z * M2.z + v.w * M2.w;
            p.w = 0.f;
            pstrip[rl * 33 + kk] = p;
        }
        // wave-local reduce: lanes 0..47 -> (ro, s), 32 partials each
        if (l < 48) {
            int ro = l / 3, s = l - ro * 3;
            const float* pr = (const float*)&pstrip[ro * 33] + s;
            float acc = 0.f;
            #pragma unroll
            for (int k = 0; k < 32; k++) acc += pr[k * 4];
            pw[cc * 48 + l] = acc;
        }
        // stream this chunk's outputs: 64 b x 12 quads, all 64 lanes, 12 iters
        {
            int f  = l;                 // flat = b*12 + dp
            int b  = f / 12;
            int dp = f - b * 12;
            #pragma unroll
            for (int j = 0; j < 12; j++) {
                int p4 = cc * 12 + dp;
                f32x4 pv = *(const f32x4*)&pw[p4 * 4];
                int s0 = p4 % 3;        // (4*p4)%3 == p4%3
                int s1 = (s0 + 1 == 3) ? 0 : s0 + 1;
                int s2 = (s1 + 1 == 3) ? 0 : s1 + 1;
                const float* pe = &pel[b * 3];
                f32x4 o;
                o.x = fmaxf(pv.x + pe[s0], 0.f);
                o.y = fmaxf(pv.y + pe[s1], 0.f);
                o.z = fmaxf(pv.z + pe[s2], 0.f);
                o.w = fmaxf(pv.w + pe[s0], 0.f);
                __builtin_nontemporal_store(o, (f32x4*)(ob + (size_t)b * (C_ * BINS_ * 3)) + p4);
                b += 5; dp += 4;        // f += 64 = 5*12 + 4
                if (dp >= 12) { dp -= 12; b += 1; }
            }
        }
    }
}

extern "C" void kernel_launch(void* const* d_in, const int* in_sizes, int n_in,
                              void* d_out, int out_size, void* d_ws, size_t ws_size,
                              hipStream_t stream) {
    const float* eos   = (const float*)d_in[0];
    const float* table = (const float*)d_in[1];
    const float* Wb    = (const float*)d_in[2];
    const float* We    = (const float*)d_in[3];
    const float* be    = (const float*)d_in[4];
    const float* Wfc   = (const float*)d_in[5];
    const float* bfc   = (const float*)d_in[6];
    float* out = (float*)d_out;
    float* ws  = (float*)d_ws;

    kprep<<<73, 256, 0, stream>>>(Wb, We, be, Wfc, bfc, ws);
    kpe<<<368, 256, 0, stream>>>(eos, ws);
    dim3 g(32, 23);
    kmain<<<g, 256, 0, stream>>>(table, ws, out);
}

// Round 10
// 52.008 us; speedup vs baseline: 1.0785x; 1.0785x over previous
//
#include <hip/hip_runtime.h>

#define B_    64
#define C_    23
#define E_    1024
#define D_    1024
#define BOT_  128
#define BINS_ 8192
#define S_    3
#define NUMBINS (C_*BINS_)

typedef float f32x4 __attribute__((ext_vector_type(4)));

// Raw barrier: does NOT drain vmcnt (unlike __syncthreads). LDS ordering via
// explicit lgkmcnt(0). sched_barrier(0) pins ordering (guide rule 18).
#define LDS_BARRIER() do {                                   \
    asm volatile("s_waitcnt lgkmcnt(0)" ::: "memory");       \
    __builtin_amdgcn_sched_barrier(0);                       \
    __builtin_amdgcn_s_barrier();                            \
    __builtin_amdgcn_sched_barrier(0);                       \
} while (0)

// ws layout (floats):
// [0,384)            M  : M[s*128+k]   = sum_d Wfc[s][d]      * Wb[d][k]
// [512,512+3072)     N  : N[s*1024+e]  = sum_d Wfc[s][1024+d] * We[d][e]
// [3584,3587)        c0 : c0[s]
// [3600,3600+4416)   pe : pe[(b*C+c)*3+s]
#define WS_M   0
#define WS_N   512
#define WS_C0  3584
#define WS_PE  3600

// grid 73: [0,64): N (e0 = bx*16, all 3 s)  [64,72): M (k0=(bx-64)*16)  72: c0
__global__ __launch_bounds__(256) void kprep(const float* __restrict__ Wb,
                                             const float* __restrict__ We,
                                             const float* __restrict__ be,
                                             const float* __restrict__ Wfc,
                                             const float* __restrict__ bfc,
                                             float* __restrict__ ws) {
    const int bx = blockIdx.x;
    const int t  = threadIdx.x;

    if (bx == 72) {                // c0
        int wave = t >> 6, lane = t & 63;
        if (wave < 3) {
            const float* w2 = Wfc + wave * 2 * D_ + D_;
            float acc = 0.f;
            #pragma unroll
            for (int j = 0; j < D_ / 64; j++) {
                int d = lane + j * 64;
                acc += w2[d] * be[d];
            }
            #pragma unroll
            for (int off = 32; off; off >>= 1) acc += __shfl_down(acc, off);
            if (lane == 0) ws[WS_C0 + wave] = acc + bfc[wave];
        }
        return;
    }

    __shared__ float wv[3072];     // 3 broadcast rows of Wfc (w1 or w2)
    __shared__ float red[256];

    const int og   = t & 15;       // output within the 16-chunk
    const int dgrp = t >> 4;       // 0..15, each owns 64 d's

    const float* src;              // matrix: src[d*ostride + obase + og]
    int ostride, obase, wofs;
    float* dst0;                   // + s*dstride
    int dstride;

    if (bx < 64) {                 // N[s][e0+og]
        int e0 = bx * 16;
        src = We; ostride = E_; obase = e0; wofs = D_;
        dst0 = ws + WS_N + e0; dstride = E_;
    } else {                       // M[s][k0+og]
        int k0 = (bx - 64) * 16;
        src = Wb; ostride = BOT_; obase = k0; wofs = 0;
        dst0 = ws + WS_M + k0; dstride = BOT_;
    }

    for (int i = t; i < 3072; i += 256) {
        int s = i >> 10, d = i & 1023;
        wv[i] = Wfc[s * 2 * D_ + wofs + d];
    }
    __syncthreads();

    const float* p  = src + (size_t)(dgrp * 64) * ostride + obase + og;
    const float* w0 = wv + dgrp * 64;
    float a0 = 0.f, a1 = 0.f, a2 = 0.f;
    #pragma unroll 8
    for (int i = 0; i < 64; i++) {
        float v = p[(size_t)i * ostride];
        a0 += w0[i] * v;
        a1 += w0[1024 + i] * v;
        a2 += w0[2048 + i] * v;
    }
    float accs[3] = {a0, a1, a2};
    for (int s = 0; s < 3; s++) {
        __syncthreads();
        red[t] = accs[s];
        #pragma unroll
        for (int off = 128; off >= 16; off >>= 1) {
            __syncthreads();
            if (t < off) red[t] += red[t + off];
        }
        if (t < 16) dst0[s * dstride + t] = red[t];
    }
}

// one wave per (b,c) row: pe = eos_emb[row]·N[s] + c0[s]
__global__ __launch_bounds__(256) void kpe(const float* __restrict__ eos,
                                           float* ws) {
    int wave = threadIdx.x >> 6;
    int lane = threadIdx.x & 63;
    int row  = blockIdx.x * 4 + wave;      // 0..B*C-1 (=1471)
    const float* x  = eos + (size_t)row * E_;
    const float* N0 = ws + WS_N;
    float a0 = 0.f, a1 = 0.f, a2 = 0.f;
    #pragma unroll
    for (int j = 0; j < E_ / 64; j++) {
        int i = lane + j * 64;
        float v = x[i];
        a0 += v * N0[i];
        a1 += v * N0[1024 + i];
        a2 += v * N0[2048 + i];
    }
    #pragma unroll
    for (int off = 32; off; off >>= 1) {
        a0 += __shfl_down(a0, off);
        a1 += __shfl_down(a1, off);
        a2 += __shfl_down(a2, off);
    }
    if (lane == 0) {
        float* pe = ws + WS_PE + row * 3;
        pe[0] = a0 + ws[WS_C0 + 0];
        pe[1] = a1 + ws[WS_C0 + 1];
        pe[2] = a2 + ws[WS_C0 + 2];
    }
}

// grid (32, 23): block = (c=blockIdx.y, n0 = blockIdx.x*256).
// R7 structure with RAW barriers (no vmcnt drain): per 64-row batch,
// coalesced 1KB/instr table reads (reg double-buffer — prefetch now truly
// stays in flight across reduce+stores+next partials), padded-LDS partials
// (stride 97, conflict-free), 192-thread reduce, then the batch's output
// slice NT-streamed. Only LDS is ordered at barriers (lgkmcnt(0)); global
// loads get precise compiler vmcnt at first use; NT stores never block.
__global__ __launch_bounds__(256) void kmain(const float* __restrict__ table,
                                             const float* __restrict__ ws,
                                             float* __restrict__ out) {
    const int t  = threadIdx.x;
    const int c  = blockIdx.y;
    const int n0 = blockIdx.x * 256;

    const int w  = t >> 6;         // wave 0..3
    const int l  = t & 63;
    const int h  = l >> 5;         // row parity within pair
    const int kk = l & 31;         // f32x4 quad within row

    __shared__ float P[64 * 97];   // partials, padded stride 97 (conflict-free)
    __shared__ float pbl[192];     // this batch's pb[row_local*3+s]
    __shared__ float pel[192];     // pe[b*3+s] for this c

    // per-lane M coefficients: M[s][kk*4 .. kk*4+3]
    f32x4 M0 = ((const f32x4*)(ws + WS_M      ))[kk];
    f32x4 M1 = ((const f32x4*)(ws + WS_M + 128))[kk];
    f32x4 M2 = ((const f32x4*)(ws + WS_M + 256))[kk];

    if (t < 192) {
        int b = t / 3, s = t - b * 3;
        pel[t] = ws[WS_PE + (b * C_ + c) * 3 + s];
    }

    const float* base = table + (size_t)(1 + c * BINS_ + n0) * BOT_ + kk * 4;

    f32x4 va[8], vb[8];
    #pragma unroll
    for (int i = 0; i < 8; i++) {
        int rl = (w * 8 + i) * 2 + h;
        va[i] = *(const f32x4*)(base + (size_t)rl * BOT_);
    }

    LDS_BARRIER();                 // pel visible (also orders nothing else)

    #pragma unroll
    for (int bb = 0; bb < 4; bb++) {
        // partials for batch bb from the live register buffer
        #pragma unroll
        for (int i = 0; i < 8; i++) {
            int rl = (w * 8 + i) * 2 + h;
            f32x4 v = (bb & 1) ? vb[i] : va[i];
            float* pp = &P[rl * 97 + kk * 3];
            pp[0] = v.x * M0.x + v.y * M0.y + v.z * M0.z + v.w * M0.w;
            pp[1] = v.x * M1.x + v.y * M1.y + v.z * M1.z + v.w * M1.w;
            pp[2] = v.x * M2.x + v.y * M2.y + v.z * M2.z + v.w * M2.w;
        }
        // issue next batch's loads; they stay outstanding across the raw
        // barriers and are waited (precisely) only at next batch's use
        if (bb < 3) {
            #pragma unroll
            for (int i = 0; i < 8; i++) {
                int rl = (w * 8 + i) * 2 + h;
                f32x4 ld = *(const f32x4*)(base + (size_t)((bb + 1) * 64 + rl) * BOT_);
                if (bb & 1) va[i] = ld; else vb[i] = ld;
            }
        }
        LDS_BARRIER();             // P visible to reducers
        // reduce: 192 threads, s = t>>6, local row = t&63
        if (t < 192) {
            int s = t >> 6, ro = t & 63;
            const float* pr = &P[ro * 97 + s];
            float acc = 0.f;
            #pragma unroll
            for (int k = 0; k < 32; k++) acc += pr[k * 3];
            pbl[ro * 3 + s] = acc;
        }
        LDS_BARRIER();             // pbl visible; P free for next batch
        // stream this batch's outputs: 64 b-slices x 48 f32x4, all 256 threads
        {
            int b  = t / 48;
            int p4 = t - b * 48;
            const float* ob = out + ((size_t)c * BINS_ + n0 + bb * 64) * 3;
            #pragma unroll
            for (int j = 0; j < 12; j++) {
                f32x4 pv = *(const f32x4*)&pbl[p4 * 4];
                int s0 = p4 % 3;            // (4*p4)%3 == p4%3
                int s1 = (s0 + 1 == 3) ? 0 : s0 + 1;
                int s2 = (s1 + 1 == 3) ? 0 : s1 + 1;
                const float* pe = &pel[b * 3];
                f32x4 o;
                o.x = fmaxf(pv.x + pe[s0], 0.f);
                o.y = fmaxf(pv.y + pe[s1], 0.f);
                o.z = fmaxf(pv.z + pe[s2], 0.f);
                o.w = fmaxf(pv.w + pe[s0], 0.f);
                f32x4* dst = (f32x4*)(ob + (size_t)b * (C_ * BINS_ * 3)) + p4;
                __builtin_nontemporal_store(o, dst);
                b += 5; p4 += 16;           // q += 256 = 5*48 + 16
                if (p4 >= 48) { p4 -= 48; b += 1; }
            }
        }
    }
}

extern "C" void kernel_launch(void* const* d_in, const int* in_sizes, int n_in,
                              void* d_out, int out_size, void* d_ws, size_t ws_size,
                              hipStream_t stream) {
    const float* eos   = (const float*)d_in[0];
    const float* table = (const float*)d_in[1];
    const float* Wb    = (const float*)d_in[2];
    const float* We    = (const float*)d_in[3];
    const float* be    = (const float*)d_in[4];
    const float* Wfc   = (const float*)d_in[5];
    const float* bfc   = (const float*)d_in[6];
    float* out = (float*)d_out;
    float* ws  = (float*)d_ws;

    kprep<<<73, 256, 0, stream>>>(Wb, We, be, Wfc, bfc, ws);
    kpe<<<368, 256, 0, stream>>>(eos, ws);
    dim3 g(32, 23);
    kmain<<<g, 256, 0, stream>>>(table, ws, out);
}

// Round 11
// 48.678 us; speedup vs baseline: 1.1523x; 1.0684x over previous
//
#include <hip/hip_runtime.h>

#define B_    64
#define C_    23
#define E_    1024
#define D_    1024
#define BOT_  128
#define BINS_ 8192
#define S_    3
#define NUMBINS (C_*BINS_)

typedef float f32x4 __attribute__((ext_vector_type(4)));

// Raw barrier: does NOT drain vmcnt (unlike __syncthreads). LDS ordering via
// explicit lgkmcnt(0). sched_barrier(0) pins ordering (guide rule 18).
#define LDS_BARRIER() do {                                   \
    asm volatile("s_waitcnt lgkmcnt(0)" ::: "memory");       \
    __builtin_amdgcn_sched_barrier(0);                       \
    __builtin_amdgcn_s_barrier();                            \
    __builtin_amdgcn_sched_barrier(0);                       \
} while (0)

// ws layout (floats):
// [0,384)            M  : M[s*128+k]   = sum_d Wfc[s][d]      * Wb[d][k]
// [512,512+3072)     N  : N[s*1024+e]  = sum_d Wfc[s][1024+d] * We[d][e]
// [3584,3587)        c0 : c0[s]
// [3600,3600+4416)   pe : pe[(b*C+c)*3+s]
#define WS_M   0
#define WS_N   512
#define WS_C0  3584
#define WS_PE  3600

// grid 145: [0,128): N (e0 = bx*8)  [128,144): M (k0 = (bx-128)*8)  144: c0
// 256 thr = 4 waves x (8 og x 8 dg); wave owns d-slice [w*256, w*256+256),
// thread chain = 32; dgrp-reduce = 9 shfl_xor (in-wave); 4-wave fold via
// 384B LDS + one barrier. Wfc read direct (L1-resident, 8-lane broadcast).
__global__ __launch_bounds__(256) void kprep(const float* __restrict__ Wb,
                                             const float* __restrict__ We,
                                             const float* __restrict__ be,
                                             const float* __restrict__ Wfc,
                                             const float* __restrict__ bfc,
                                             float* __restrict__ ws) {
    const int bx = blockIdx.x;
    const int t  = threadIdx.x;

    if (bx == 144) {               // c0
        int wave = t >> 6, lane = t & 63;
        if (wave < 3) {
            const float* w2 = Wfc + wave * 2 * D_ + D_;
            float acc = 0.f;
            #pragma unroll
            for (int j = 0; j < D_ / 64; j++) {
                int d = lane + j * 64;
                acc += w2[d] * be[d];
            }
            #pragma unroll
            for (int off = 32; off; off >>= 1) acc += __shfl_down(acc, off);
            if (lane == 0) ws[WS_C0 + wave] = acc + bfc[wave];
        }
        return;
    }

    const int w  = t >> 6;         // wave 0..3 -> d-slice
    const int l  = t & 63;
    const int og = l & 7;          // output within the 8-chunk
    const int dg = l >> 3;         // 0..7, chain 32 within wave slice

    const float* src;
    int ostride, obase, wofs;
    float* dst0;
    int dstride;

    if (bx < 128) {                // N[s][e0+og]
        int e0 = bx * 8;
        src = We; ostride = E_; obase = e0; wofs = D_;
        dst0 = ws + WS_N + e0; dstride = E_;
    } else {                       // M[s][k0+og]
        int k0 = (bx - 128) * 8;
        src = Wb; ostride = BOT_; obase = k0; wofs = 0;
        dst0 = ws + WS_M + k0; dstride = BOT_;
    }

    const int d0 = w * 256 + dg * 32;
    const float* p  = src + (size_t)d0 * ostride + obase + og;
    const float* wf = Wfc + wofs + d0;      // + s*2*D_

    float a0 = 0.f, a1 = 0.f, a2 = 0.f;
    #pragma unroll 8
    for (int i = 0; i < 32; i++) {
        float v = p[(size_t)i * ostride];
        a0 += wf[i] * v;
        a1 += wf[2 * D_ + i] * v;
        a2 += wf[4 * D_ + i] * v;
    }
    #pragma unroll
    for (int mask = 8; mask <= 32; mask <<= 1) {
        a0 += __shfl_xor(a0, mask);
        a1 += __shfl_xor(a1, mask);
        a2 += __shfl_xor(a2, mask);
    }

    __shared__ float red[4][8][3];
    if (l < 8) {                    // og = l, dg = 0 holds the wave's sums
        red[w][l][0] = a0; red[w][l][1] = a1; red[w][l][2] = a2;
    }
    __syncthreads();
    if (t < 24) {
        int o2 = t / 3, s = t - o2 * 3;
        dst0[s * dstride + o2] = red[0][o2][s] + red[1][o2][s]
                               + red[2][o2][s] + red[3][o2][s];
    }
}

// one wave per (b,c) row: pe = eos_emb[row]·N[s] + c0[s]  (f32x4 loads)
__global__ __launch_bounds__(256) void kpe(const float* __restrict__ eos,
                                           float* ws) {
    int wave = threadIdx.x >> 6;
    int lane = threadIdx.x & 63;
    int row  = blockIdx.x * 4 + wave;      // 0..B*C-1 (=1471)
    const f32x4* xq = (const f32x4*)(eos + (size_t)row * E_);
    const f32x4* Nq = (const f32x4*)(ws + WS_N);
    float a0 = 0.f, a1 = 0.f, a2 = 0.f;
    #pragma unroll
    for (int j = 0; j < 4; j++) {
        int q = lane + 64 * j;
        f32x4 v  = xq[q];
        f32x4 n0 = Nq[q], n1 = Nq[256 + q], n2 = Nq[512 + q];
        a0 += v.x * n0.x + v.y * n0.y + v.z * n0.z + v.w * n0.w;
        a1 += v.x * n1.x + v.y * n1.y + v.z * n1.z + v.w * n1.w;
        a2 += v.x * n2.x + v.y * n2.y + v.z * n2.z + v.w * n2.w;
    }
    #pragma unroll
    for (int off = 32; off; off >>= 1) {
        a0 += __shfl_down(a0, off);
        a1 += __shfl_down(a1, off);
        a2 += __shfl_down(a2, off);
    }
    if (lane == 0) {
        float* pe = ws + WS_PE + row * 3;
        pe[0] = a0 + ws[WS_C0 + 0];
        pe[1] = a1 + ws[WS_C0 + 1];
        pe[2] = a2 + ws[WS_C0 + 2];
    }
}

// grid (32, 23): block = (c=blockIdx.y, n0 = blockIdx.x*256).
// R7 structure with RAW barriers (no vmcnt drain): per 64-row batch,
// coalesced 1KB/instr table reads (reg double-buffer), padded-LDS partials
// (stride 97, conflict-free), 192-thread reduce, then the batch's output
// slice NT-streamed. Only LDS is ordered at barriers (lgkmcnt(0)).
__global__ __launch_bounds__(256) void kmain(const float* __restrict__ table,
                                             const float* __restrict__ ws,
                                             float* __restrict__ out) {
    const int t  = threadIdx.x;
    const int c  = blockIdx.y;
    const int n0 = blockIdx.x * 256;

    const int w  = t >> 6;         // wave 0..3
    const int l  = t & 63;
    const int h  = l >> 5;         // row parity within pair
    const int kk = l & 31;         // f32x4 quad within row

    __shared__ float P[64 * 97];   // partials, padded stride 97 (conflict-free)
    __shared__ float pbl[192];     // this batch's pb[row_local*3+s]
    __shared__ float pel[192];     // pe[b*3+s] for this c

    // per-lane M coefficients: M[s][kk*4 .. kk*4+3]
    f32x4 M0 = ((const f32x4*)(ws + WS_M      ))[kk];
    f32x4 M1 = ((const f32x4*)(ws + WS_M + 128))[kk];
    f32x4 M2 = ((const f32x4*)(ws + WS_M + 256))[kk];

    if (t < 192) {
        int b = t / 3, s = t - b * 3;
        pel[t] = ws[WS_PE + (b * C_ + c) * 3 + s];
    }

    const float* base = table + (size_t)(1 + c * BINS_ + n0) * BOT_ + kk * 4;

    f32x4 va[8], vb[8];
    #pragma unroll
    for (int i = 0; i < 8; i++) {
        int rl = (w * 8 + i) * 2 + h;
        va[i] = *(const f32x4*)(base + (size_t)rl * BOT_);
    }

    LDS_BARRIER();                 // pel visible

    #pragma unroll
    for (int bb = 0; bb < 4; bb++) {
        #pragma unroll
        for (int i = 0; i < 8; i++) {
            int rl = (w * 8 + i) * 2 + h;
            f32x4 v = (bb & 1) ? vb[i] : va[i];
            float* pp = &P[rl * 97 + kk * 3];
            pp[0] = v.x * M0.x + v.y * M0.y + v.z * M0.z + v.w * M0.w;
            pp[1] = v.x * M1.x + v.y * M1.y + v.z * M1.z + v.w * M1.w;
            pp[2] = v.x * M2.x + v.y * M2.y + v.z * M2.z + v.w * M2.w;
        }
        if (bb < 3) {
            #pragma unroll
            for (int i = 0; i < 8; i++) {
                int rl = (w * 8 + i) * 2 + h;
                f32x4 ld = *(const f32x4*)(base + (size_t)((bb + 1) * 64 + rl) * BOT_);
                if (bb & 1) va[i] = ld; else vb[i] = ld;
            }
        }
        LDS_BARRIER();             // P visible to reducers
        if (t < 192) {
            int s = t >> 6, ro = t & 63;
            const float* pr = &P[ro * 97 + s];
            float acc = 0.f;
            #pragma unroll
            for (int k = 0; k < 32; k++) acc += pr[k * 3];
            pbl[ro * 3 + s] = acc;
        }
        LDS_BARRIER();             // pbl visible; P free for next batch
        {
            int b  = t / 48;
            int p4 = t - b * 48;
            const float* ob = out + ((size_t)c * BINS_ + n0 + bb * 64) * 3;
            #pragma unroll
            for (int j = 0; j < 12; j++) {
                f32x4 pv = *(const f32x4*)&pbl[p4 * 4];
                int s0 = p4 % 3;            // (4*p4)%3 == p4%3
                int s1 = (s0 + 1 == 3) ? 0 : s0 + 1;
                int s2 = (s1 + 1 == 3) ? 0 : s1 + 1;
                const float* pe = &pel[b * 3];
                f32x4 o;
                o.x = fmaxf(pv.x + pe[s0], 0.f);
                o.y = fmaxf(pv.y + pe[s1], 0.f);
                o.z = fmaxf(pv.z + pe[s2], 0.f);
                o.w = fmaxf(pv.w + pe[s0], 0.f);
                f32x4* dst = (f32x4*)(ob + (size_t)b * (C_ * BINS_ * 3)) + p4;
                __builtin_nontemporal_store(o, dst);
                b += 5; p4 += 16;           // q += 256 = 5*48 + 16
                if (p4 >= 48) { p4 -= 48; b += 1; }
            }
        }
    }
}

extern "C" void kernel_launch(void* const* d_in, const int* in_sizes, int n_in,
                              void* d_out, int out_size, void* d_ws, size_t ws_size,
                              hipStream_t stream) {
    const float* eos   = (const float*)d_in[0];
    const float* table = (const float*)d_in[1];
    const float* Wb    = (const float*)d_in[2];
    const float* We    = (const float*)d_in[3];
    const float* be    = (const float*)d_in[4];
    const float* Wfc   = (const float*)d_in[5];
    const float* bfc   = (const float*)d_in[6];
    float* out = (float*)d_out;
    float* ws  = (float*)d_ws;

    kprep<<<145, 256, 0, stream>>>(Wb, We, be, Wfc, bfc, ws);
    kpe<<<368, 256, 0, stream>>>(eos, ws);
    dim3 g(32, 23);
    kmain<<<g, 256, 0, stream>>>(table, ws, out);
}

// Round 12
// 48.510 us; speedup vs baseline: 1.1563x; 1.0035x over previous
//
#include <hip/hip_runtime.h>

#define B_    64
#define C_    23
#define E_    1024
#define D_    1024
#define BOT_  128
#define BINS_ 8192
#define S_    3
#define NUMBINS (C_*BINS_)

typedef float f32x4 __attribute__((ext_vector_type(4)));

// Raw barrier: does NOT drain vmcnt (unlike __syncthreads). LDS ordering via
// explicit lgkmcnt(0). sched_barrier(0) pins ordering (guide rule 18).
#define LDS_BARRIER() do {                                   \
    asm volatile("s_waitcnt lgkmcnt(0)" ::: "memory");       \
    __builtin_amdgcn_sched_barrier(0);                       \
    __builtin_amdgcn_s_barrier();                            \
    __builtin_amdgcn_sched_barrier(0);                       \
} while (0)

// ws layout (floats):
// [0,384)            M  : M[s*128+k]   = sum_d Wfc[s][d]      * Wb[d][k]
// [512,512+3072)     N  : N[s*1024+e]  = sum_d Wfc[s][1024+d] * We[d][e]
// [3584,3587)        c0 : c0[s]
// [3600,3600+4416)   pe : pe[(b*C+c)*3+s]
#define WS_M   0
#define WS_N   512
#define WS_C0  3584
#define WS_PE  3600

// grid 145: [0,128): N (e0 = bx*8)  [128,144): M (k0 = (bx-128)*8)  144: c0
// 256 thr = 4 waves x (8 og x 8 dg); wave owns d-slice [w*256, w*256+256),
// thread chain = 32; dgrp-reduce = 9 shfl_xor (in-wave); 4-wave fold via
// 384B LDS + one barrier. Wfc read direct (L1-resident, 8-lane broadcast).
__global__ __launch_bounds__(256) void kprep(const float* __restrict__ Wb,
                                             const float* __restrict__ We,
                                             const float* __restrict__ be,
                                             const float* __restrict__ Wfc,
                                             const float* __restrict__ bfc,
                                             float* __restrict__ ws) {
    const int bx = blockIdx.x;
    const int t  = threadIdx.x;

    if (bx == 144) {               // c0
        int wave = t >> 6, lane = t & 63;
        if (wave < 3) {
            const float* w2 = Wfc + wave * 2 * D_ + D_;
            float acc = 0.f;
            #pragma unroll
            for (int j = 0; j < D_ / 64; j++) {
                int d = lane + j * 64;
                acc += w2[d] * be[d];
            }
            #pragma unroll
            for (int off = 32; off; off >>= 1) acc += __shfl_down(acc, off);
            if (lane == 0) ws[WS_C0 + wave] = acc + bfc[wave];
        }
        return;
    }

    const int w  = t >> 6;         // wave 0..3 -> d-slice
    const int l  = t & 63;
    const int og = l & 7;          // output within the 8-chunk
    const int dg = l >> 3;         // 0..7, chain 32 within wave slice

    const float* src;
    int ostride, obase, wofs;
    float* dst0;
    int dstride;

    if (bx < 128) {                // N[s][e0+og]
        int e0 = bx * 8;
        src = We; ostride = E_; obase = e0; wofs = D_;
        dst0 = ws + WS_N + e0; dstride = E_;
    } else {                       // M[s][k0+og]
        int k0 = (bx - 128) * 8;
        src = Wb; ostride = BOT_; obase = k0; wofs = 0;
        dst0 = ws + WS_M + k0; dstride = BOT_;
    }

    const int d0 = w * 256 + dg * 32;
    const float* p  = src + (size_t)d0 * ostride + obase + og;
    const float* wf = Wfc + wofs + d0;      // + s*2*D_

    float a0 = 0.f, a1 = 0.f, a2 = 0.f;
    #pragma unroll 8
    for (int i = 0; i < 32; i++) {
        float v = p[(size_t)i * ostride];
        a0 += wf[i] * v;
        a1 += wf[2 * D_ + i] * v;
        a2 += wf[4 * D_ + i] * v;
    }
    #pragma unroll
    for (int mask = 8; mask <= 32; mask <<= 1) {
        a0 += __shfl_xor(a0, mask);
        a1 += __shfl_xor(a1, mask);
        a2 += __shfl_xor(a2, mask);
    }

    __shared__ float red[4][8][3];
    if (l < 8) {                    // og = l, dg = 0 holds the wave's sums
        red[w][l][0] = a0; red[w][l][1] = a1; red[w][l][2] = a2;
    }
    __syncthreads();
    if (t < 24) {
        int o2 = t / 3, s = t - o2 * 3;
        dst0[s * dstride + o2] = red[0][o2][s] + red[1][o2][s]
                               + red[2][o2][s] + red[3][o2][s];
    }
}

// one wave per (b,c) row: pe = eos_emb[row]·N[s] + c0[s]  (f32x4 loads)
__global__ __launch_bounds__(256) void kpe(const float* __restrict__ eos,
                                           float* ws) {
    int wave = threadIdx.x >> 6;
    int lane = threadIdx.x & 63;
    int row  = blockIdx.x * 4 + wave;      // 0..B*C-1 (=1471)
    const f32x4* xq = (const f32x4*)(eos + (size_t)row * E_);
    const f32x4* Nq = (const f32x4*)(ws + WS_N);
    float a0 = 0.f, a1 = 0.f, a2 = 0.f;
    #pragma unroll
    for (int j = 0; j < 4; j++) {
        int q = lane + 64 * j;
        f32x4 v  = xq[q];
        f32x4 n0 = Nq[q], n1 = Nq[256 + q], n2 = Nq[512 + q];
        a0 += v.x * n0.x + v.y * n0.y + v.z * n0.z + v.w * n0.w;
        a1 += v.x * n1.x + v.y * n1.y + v.z * n1.z + v.w * n1.w;
        a2 += v.x * n2.x + v.y * n2.y + v.z * n2.z + v.w * n2.w;
    }
    #pragma unroll
    for (int off = 32; off; off >>= 1) {
        a0 += __shfl_down(a0, off);
        a1 += __shfl_down(a1, off);
        a2 += __shfl_down(a2, off);
    }
    if (lane == 0) {
        float* pe = ws + WS_PE + row * 3;
        pe[0] = a0 + ws[WS_C0 + 0];
        pe[1] = a1 + ws[WS_C0 + 1];
        pe[2] = a2 + ws[WS_C0 + 2];
    }
}

// grid (64, 23): block = (c=blockIdx.y, n0 = blockIdx.x*128) -- 1472 blocks,
// ~5.75 resident blocks/CU (LDS 26KB caps at 6) vs 2.9 before: doubles the
// concurrent read+write streams per CU. Inner structure identical to R10:
// per 64-row batch (2 batches), coalesced 1KB/instr table reads (reg dbuf),
// padded-LDS partials (stride 97, conflict-free), 192-thread reduce, then
// the batch's output slice NT-streamed. Raw barriers (lgkmcnt only).
__global__ __launch_bounds__(256) void kmain(const float* __restrict__ table,
                                             const float* __restrict__ ws,
                                             float* __restrict__ out) {
    const int t  = threadIdx.x;
    const int c  = blockIdx.y;
    const int n0 = blockIdx.x * 128;

    const int w  = t >> 6;         // wave 0..3
    const int l  = t & 63;
    const int h  = l >> 5;         // row parity within pair
    const int kk = l & 31;         // f32x4 quad within row

    __shared__ float P[64 * 97];   // partials, padded stride 97 (conflict-free)
    __shared__ float pbl[192];     // this batch's pb[row_local*3+s]
    __shared__ float pel[192];     // pe[b*3+s] for this c

    // per-lane M coefficients: M[s][kk*4 .. kk*4+3]
    f32x4 M0 = ((const f32x4*)(ws + WS_M      ))[kk];
    f32x4 M1 = ((const f32x4*)(ws + WS_M + 128))[kk];
    f32x4 M2 = ((const f32x4*)(ws + WS_M + 256))[kk];

    if (t < 192) {
        int b = t / 3, s = t - b * 3;
        pel[t] = ws[WS_PE + (b * C_ + c) * 3 + s];
    }

    const float* base = table + (size_t)(1 + c * BINS_ + n0) * BOT_ + kk * 4;

    f32x4 va[8], vb[8];
    #pragma unroll
    for (int i = 0; i < 8; i++) {
        int rl = (w * 8 + i) * 2 + h;
        va[i] = *(const f32x4*)(base + (size_t)rl * BOT_);
    }

    LDS_BARRIER();                 // pel visible

    #pragma unroll
    for (int bb = 0; bb < 2; bb++) {
        #pragma unroll
        for (int i = 0; i < 8; i++) {
            int rl = (w * 8 + i) * 2 + h;
            f32x4 v = (bb & 1) ? vb[i] : va[i];
            float* pp = &P[rl * 97 + kk * 3];
            pp[0] = v.x * M0.x + v.y * M0.y + v.z * M0.z + v.w * M0.w;
            pp[1] = v.x * M1.x + v.y * M1.y + v.z * M1.z + v.w * M1.w;
            pp[2] = v.x * M2.x + v.y * M2.y + v.z * M2.z + v.w * M2.w;
        }
        // issue next batch's loads; stay outstanding across raw barriers
        if (bb < 1) {
            #pragma unroll
            for (int i = 0; i < 8; i++) {
                int rl = (w * 8 + i) * 2 + h;
                f32x4 ld = *(const f32x4*)(base + (size_t)(64 + rl) * BOT_);
                vb[i] = ld;
            }
        }
        LDS_BARRIER();             // P visible to reducers
        if (t < 192) {
            int s = t >> 6, ro = t & 63;
            const float* pr = &P[ro * 97 + s];
            float acc = 0.f;
            #pragma unroll
            for (int k = 0; k < 32; k++) acc += pr[k * 3];
            pbl[ro * 3 + s] = acc;
        }
        LDS_BARRIER();             // pbl visible; P free for next batch
        {
            int b  = t / 48;
            int p4 = t - b * 48;
            const float* ob = out + ((size_t)c * BINS_ + n0 + bb * 64) * 3;
            #pragma unroll
            for (int j = 0; j < 12; j++) {
                f32x4 pv = *(const f32x4*)&pbl[p4 * 4];
                int s0 = p4 % 3;            // (4*p4)%3 == p4%3
                int s1 = (s0 + 1 == 3) ? 0 : s0 + 1;
                int s2 = (s1 + 1 == 3) ? 0 : s1 + 1;
                const float* pe = &pel[b * 3];
                f32x4 o;
                o.x = fmaxf(pv.x + pe[s0], 0.f);
                o.y = fmaxf(pv.y + pe[s1], 0.f);
                o.z = fmaxf(pv.z + pe[s2], 0.f);
                o.w = fmaxf(pv.w + pe[s0], 0.f);
                f32x4* dst = (f32x4*)(ob + (size_t)b * (C_ * BINS_ * 3)) + p4;
                __builtin_nontemporal_store(o, dst);
                b += 5; p4 += 16;           // q += 256 = 5*48 + 16
                if (p4 >= 48) { p4 -= 48; b += 1; }
            }
        }
    }
}

extern "C" void kernel_launch(void* const* d_in, const int* in_sizes, int n_in,
                              void* d_out, int out_size, void* d_ws, size_t ws_size,
                              hipStream_t stream) {
    const float* eos   = (const float*)d_in[0];
    const float* table = (const float*)d_in[1];
    const float* Wb    = (const float*)d_in[2];
    const float* We    = (const float*)d_in[3];
    const float* be    = (const float*)d_in[4];
    const float* Wfc   = (const float*)d_in[5];
    const float* bfc   = (const float*)d_in[6];
    float* out = (float*)d_out;
    float* ws  = (float*)d_ws;

    kprep<<<145, 256, 0, stream>>>(Wb, We, be, Wfc, bfc, ws);
    kpe<<<368, 256, 0, stream>>>(eos, ws);
    dim3 g(64, 23);
    kmain<<<g, 256, 0, stream>>>(table, ws, out);
}